// Round 4
// baseline (484.235 us; speedup 1.0000x reference)
//
#include <hip/hip_runtime.h>
#include <hip/hip_bf16.h>

#define N 384
#define HIDN 128
#define NHD 8
#define DHD 16
#define NRB 64
#define CUTF 10.0f

// ws layout (float slots)
#define WS_V 0
#define WS_QPB (WS_V + N*HIDN)                 // bf16 buffer: head-major [h][n][c]
#define WS_KPB (WS_QPB + N*NHD*HIDN/2)        // bf16 buffer: head-major [h][n][c]
#define WS_GATE (WS_KPB + N*NHD*HIDN/2)
#define WS_UPD (WS_GATE + N*NHD)
#define WS_SCORES (WS_UPD + N*HIDN)
#define WS_W2BF (WS_SCORES + NHD*N*N)         // bf16 buffer: 128*128 shorts (W2^T)

typedef short bf16x8 __attribute__((ext_vector_type(8)));
typedef float floatx4 __attribute__((ext_vector_type(4)));
#define MFMA16(a, b, c) __builtin_amdgcn_mfma_f32_16x16x32_bf16(a, b, c, 0, 0, 0)

__device__ __forceinline__ float siluf(float x) { return x / (1.0f + __expf(-x)); }
__device__ __forceinline__ float silu_fast(float x) {
    return x * __builtin_amdgcn_rcpf(1.0f + __expf(-x));
}
__device__ __forceinline__ short f2bf(float f) {
    unsigned int b = __float_as_uint(f);
    unsigned int r = (b + 0x7fffu + ((b >> 16) & 1u)) >> 16;
    return (short)r;
}
__device__ __forceinline__ float bf2f(short s) {
    return __uint_as_float(((unsigned int)(unsigned short)s) << 16);
}
// packed f32x2 -> bf16x2 (RNE), 1 instr instead of 2x5
__device__ __forceinline__ unsigned int cvt_pk_bf16(float lo, float hi) {
    unsigned int r;
    asm("v_cvt_pk_bf16_f32 %0, %1, %2" : "=v"(r) : "v"(lo), "v"(hi));
    return r;
}
__device__ __forceinline__ float wave_sum(float v) {
    for (int o = 32; o; o >>= 1) v += __shfl_down(v, o, 64);
    return v;
}

// K1: fused qkv + Qp/Kp(bf16, head-major) + gates + W2^T bf16 pre-transpose
__global__ __launch_bounds__(128) void k_pre(const float* __restrict__ ef,
    const float* __restrict__ wq, const float* __restrict__ wk, const float* __restrict__ wv,
    const float* __restrict__ aw1, const float* __restrict__ aw2,
    const float* __restrict__ gw1, const float* __restrict__ gb1,
    const float* __restrict__ gw2, const float* __restrict__ gb2,
    float* __restrict__ v, unsigned short* __restrict__ Qpb,
    unsigned short* __restrict__ Kpb, float* __restrict__ gates,
    unsigned short* __restrict__ w2bf) {
    __shared__ float sE[HIDN], sQ[HIDN], sK[HIDN], sV[HIDN];
    __shared__ float sG[NHD][2];
    int i = blockIdx.x, t = threadIdx.x;
    // blocks 0..127: also emit W2^T in bf16, row n=i, col k=t: w2bf[n][k]=aw2[k][n]
    if (i < HIDN) w2bf[(size_t)i * HIDN + t] = (unsigned short)f2bf(aw2[t * HIDN + i]);
    sE[t] = ef[i * HIDN + t];
    __syncthreads();
    float aq = 0.f, ak = 0.f, av = 0.f;
#pragma unroll 8
    for (int c = 0; c < HIDN; c++) {
        float e = sE[c];
        aq += e * wq[c * HIDN + t];
        ak += e * wk[c * HIDN + t];
        av += e * wv[c * HIDN + t];
    }
    v[i * HIDN + t] = av;
    sQ[t] = aq; sK[t] = ak; sV[t] = av;
    __syncthreads();
    for (int h = 0; h < NHD; h++) {
        float accq = 0.f, acck = 0.f;
#pragma unroll
        for (int d = 0; d < DHD; d++) {
            accq += sQ[h * DHD + d] * aw1[d * HIDN + t];
            acck += sK[h * DHD + d] * aw1[(DHD + d) * HIDN + t];
        }
        Qpb[((size_t)h * N + i) * HIDN + t] = (unsigned short)f2bf(accq);
        Kpb[((size_t)h * N + i) * HIDN + t] = (unsigned short)f2bf(acck);
        float tt = gb1[t];
#pragma unroll
        for (int d = 0; d < DHD; d++) tt += sV[h * DHD + d] * gw1[d * HIDN + t];
        float contrib = siluf(tt) * gw2[t];
        float s = wave_sum(contrib);
        if ((t & 63) == 0) sG[h][t >> 6] = s;
    }
    __syncthreads();
    if (t < NHD)
        gates[i * NHD + t] = 1.0f / (1.0f + __expf(-(sG[t][0] + sG[t][1] + gb2[0])));
}

// ---------------- K2: MFMA scores kernel ----------------
// 512 threads (8 waves), 1 head per wave. Round-2 serialized structure.
// QPB in registers (QPF), jt-split phase c (A[4] not A2[2][4]) to keep
// VGPR <= 84 (6 waves/SIMD). LDS 53888 -> 3 blocks/CU. Grid (6,N): 2304
// half-size blocks = exactly 3 full residency rounds (no tail).
#define OFF_W2T 0            // 128 rows x 256B, XOR-swizzled = 32768
#define OFF_SDD 32768        // 32 f32 = 128
#define OFF_RBF 32896        // 32 rows x 128B, XOR-swizzled = 4096
#define OFF_R   36992        // 32 rows x 528B f32 = 16896
#define SMEM_SZ 53888

__global__ __launch_bounds__(512, 6) void k_scores_mfma(
    const float* __restrict__ coords, const float* __restrict__ mask,
    const float* __restrict__ centers, const float* __restrict__ widths,
    const float* __restrict__ aw1, const float* __restrict__ ab1,
    const float* __restrict__ ab2,
    const float* __restrict__ aw3, const float* __restrict__ ab3,
    const unsigned short* __restrict__ Qpb, const unsigned short* __restrict__ Kpb,
    const unsigned short* __restrict__ w2bf,
    float* __restrict__ scores) {
    __shared__ __align__(16) char smem[SMEM_SZ];
    const int t = threadIdx.x;
    const int lane = t & 63;
    const int w = t >> 6;            // wave 0..7 == head
    const int l15 = lane & 15;
    const int quad = lane >> 4;
    const int i = blockIdx.y;
    const int jb = blockIdx.x * 64;

    // ---- phase 0: stage W2^T (swizzled); per-wave register tables ----
    {
        const uint4* src = (const uint4*)w2bf;   // 2048 x 16B
        for (int idx = t; idx < 2048; idx += 512) {
            int row = idx >> 4, slot = idx & 15;
            *(uint4*)(smem + OFF_W2T + row * 256 + ((slot * 16) ^ ((row & 7) << 4))) = src[idx];
        }
    }
    // W1r B-frags in registers: wave w covers c-tile ct=w
    const int c0 = w * 16 + l15;
    bf16x8 BW1[2];
#pragma unroll
    for (int ks = 0; ks < 2; ks++) {
        bf16x8 a;
#pragma unroll
        for (int e = 0; e < 8; e++) {
            int r = ks * 32 + quad * 8 + e;
            a[e] = f2bf(aw1[(32 + r) * HIDN + c0]);
        }
        BW1[ks] = a;
    }
    // Q-proj fragments for this head (quad-dependent): QPF[f] = Qp[h][f*32+quad*8 ..+8]
    bf16x8 QPF[4];
#pragma unroll
    for (int f = 0; f < 4; f++)
        QPF[f] = *(const bf16x8*)(Qpb + ((size_t)w * N + i) * HIDN + f * 32 + quad * 8);
    const float b1v = ab1[c0];
    const float w1dv = aw1[96 * HIDN + c0];
    const float ab3v = ab3[w];
    float b2r[8], w3r[8];
#pragma unroll
    for (int ct = 0; ct < 8; ct++) {
        b2r[ct] = ab2[ct * 16 + l15];
        w3r[ct] = aw3[(ct * 16 + l15) * NHD + w];
    }
    const float cr = centers[lane], rwd = widths[lane];
    const float cix = coords[i * 3], ciy = coords[i * 3 + 1], ciz = coords[i * 3 + 2];
    __syncthreads();

    for (int ch = 0; ch < 2; ch++) {
        const int j0 = jb + ch * 32;
        // (a) rbf + dot. r = lane, j = w + p*8
        {
#pragma unroll
            for (int p = 0; p < 4; p++) {
                int j = w + p * 8;
                int jj = j0 + j;
                float jx = coords[jj * 3], jy = coords[jj * 3 + 1], jz = coords[jj * 3 + 2];
                float dx = cix - jx, dy = ciy - jy, dz = ciz - jz;
                float dist = sqrtf(dx * dx + dy * dy + dz * dz) + 1e-8f;
                dist = fminf(fmaxf(dist, 1e-8f), 1e8f);
                float dd = dist - cr;
                float val = (dist <= CUTF) ? __expf(-rwd * dd * dd) : 0.0f;
                *(short*)(smem + OFF_RBF + j * 128 + ((lane * 2) ^ ((j & 7) << 4))) = f2bf(val);
            }
            if (t < 32) {
                int jj = j0 + t;
                float jx = coords[jj * 3], jy = coords[jj * 3 + 1], jz = coords[jj * 3 + 2];
                float dot = fminf(fmaxf(cix * jx + ciy * jy + ciz * jz, -1e8f), 1e8f);
                *(float*)(smem + OFF_SDD + t * 4) = dot;
            }
        }
        __syncthreads();
        // (b) R = (b1 + dot*w1d) + rbf@W1r. Wave w owns c-tile ct=w, both j-tiles.
#pragma unroll
        for (int jt = 0; jt < 2; jt++) {
            int jl = jt * 16 + l15;
            int sw = (jl & 7) << 4;
            bf16x8 ra0 = *(const bf16x8*)(smem + OFF_RBF + jl * 128 + ((quad * 16) ^ sw));
            bf16x8 ra1 = *(const bf16x8*)(smem + OFF_RBF + jl * 128 + ((64 + quad * 16) ^ sw));
            floatx4 acc;
#pragma unroll
            for (int r = 0; r < 4; r++) {
                float dotv = *(const float*)(smem + OFF_SDD + (jt * 16 + quad * 4 + r) * 4);
                acc[r] = b1v + dotv * w1dv;
            }
            acc = MFMA16(ra0, BW1[0], acc);
            acc = MFMA16(ra1, BW1[1], acc);
#pragma unroll
            for (int r = 0; r < 4; r++)
                *(float*)(smem + OFF_R + (jt * 16 + quad * 4 + r) * 528 + c0 * 4) = acc[r];
        }
        __syncthreads();
        // (c) strips: head h = w; jt-split to halve register state
#pragma unroll
        for (int jt = 0; jt < 2; jt++) {
            const int jl = jt * 16 + l15;
            bf16x8 A[4];
#pragma unroll
            for (int f = 0; f < 4; f++) {
                const int c8 = f * 32 + quad * 8;
                bf16x8 kp = *(const bf16x8*)(Kpb + ((size_t)w * N + j0 + jl) * HIDN + c8);
                bf16x8 qp = QPF[f];
                const char* rbase = smem + OFF_R + jl * 528 + c8 * 4;
                float4 r0 = *(const float4*)(rbase);
                float4 r1 = *(const float4*)(rbase + 16);
                float xs[8] = {r0.x, r0.y, r0.z, r0.w, r1.x, r1.y, r1.z, r1.w};
                union { unsigned int u[4]; bf16x8 v; } uu;
#pragma unroll
                for (int e2 = 0; e2 < 4; e2++) {
                    float xa = silu_fast(bf2f(kp[2 * e2])     + bf2f(qp[2 * e2])     + xs[2 * e2]);
                    float xb = silu_fast(bf2f(kp[2 * e2 + 1]) + bf2f(qp[2 * e2 + 1]) + xs[2 * e2 + 1]);
                    uu.u[e2] = cvt_pk_bf16(xa, xb);
                }
                A[f] = uu.v;
            }
            float part[4] = {0.f, 0.f, 0.f, 0.f};
#pragma unroll 2
            for (int ct = 0; ct < 8; ct++) {
                const int rw2 = ct * 16 + l15;
                const char* wb = smem + OFF_W2T + rw2 * 256;
                const int sw = (rw2 & 7) << 4;
                bf16x8 b0 = *(const bf16x8*)(wb + ((quad * 16) ^ sw));
                bf16x8 b1 = *(const bf16x8*)(wb + ((64 + quad * 16) ^ sw));
                bf16x8 b2 = *(const bf16x8*)(wb + ((128 + quad * 16) ^ sw));
                bf16x8 b3 = *(const bf16x8*)(wb + ((192 + quad * 16) ^ sw));
                float bb = b2r[ct], ww = w3r[ct];
                floatx4 acc = {bb, bb, bb, bb};
                acc = MFMA16(A[0], b0, acc);
                acc = MFMA16(A[1], b1, acc);
                acc = MFMA16(A[2], b2, acc);
                acc = MFMA16(A[3], b3, acc);
#pragma unroll
                for (int r = 0; r < 4; r++)
                    part[r] += silu_fast(acc[r]) * ww;
            }
#pragma unroll
            for (int off = 1; off < 16; off <<= 1) {
#pragma unroll
                for (int r = 0; r < 4; r++)
                    part[r] += __shfl_xor(part[r], off, 64);
            }
            if (l15 == 0) {
                const int jo = j0 + jt * 16 + quad * 4;
                float4 mv = *(const float4*)(mask + (size_t)i * N + jo);
                float4 sv;
                sv.x = fminf(fmaxf(part[0] + ab3v + mv.x, -1e9f), 1e9f);
                sv.y = fminf(fmaxf(part[1] + ab3v + mv.y, -1e9f), 1e9f);
                sv.z = fminf(fmaxf(part[2] + ab3v + mv.z, -1e9f), 1e9f);
                sv.w = fminf(fmaxf(part[3] + ab3v + mv.w, -1e9f), 1e9f);
                *(float4*)(scores + ((size_t)w * N + i) * N + jo) = sv;
            }
        }
        __syncthreads();
    }
}

// K3: softmax + attn@V + coords out + fused (upd@wo + LN) epilogue.
__global__ __launch_bounds__(256) void k_attn2(
    const float* __restrict__ scores, const float* __restrict__ v,
    const float* __restrict__ gates, const float* __restrict__ coords,
    const float* __restrict__ ef, const float* __restrict__ wo,
    const float* __restrict__ bo, const float* __restrict__ lng,
    const float* __restrict__ lnb, float* __restrict__ out) {
    __shared__ float sA[4][N];
    __shared__ float sCrd[N * 3];
    __shared__ float sC[NHD][3];
    __shared__ float sUpd[HIDN];
    __shared__ float sR2[2];
    int i = blockIdx.x, t = threadIdx.x, w = t >> 6, lane = t & 63;
    for (int idx = t; idx < N * 3; idx += 256) sCrd[idx] = coords[idx];
    float cix = coords[i * 3], ciy = coords[i * 3 + 1], ciz = coords[i * 3 + 2];
    __syncthreads();
    for (int hh = 0; hh < 2; hh++) {
        int h = hh * 4 + w;
        const float* srow = scores + ((size_t)h * N + i) * N;
        float s[6];
#pragma unroll
        for (int p = 0; p < 6; p++) s[p] = srow[lane + 64 * p];
        float m = s[0];
#pragma unroll
        for (int p = 1; p < 6; p++) m = fmaxf(m, s[p]);
        for (int off = 1; off < 64; off <<= 1) m = fmaxf(m, __shfl_xor(m, off, 64));
        float e[6], sum = 0.f;
#pragma unroll
        for (int p = 0; p < 6; p++) { e[p] = __expf(s[p] - m); sum += e[p]; }
        for (int off = 1; off < 64; off <<= 1) sum += __shfl_xor(sum, off, 64);
        float inv = 1.0f / sum;
#pragma unroll
        for (int p = 0; p < 6; p++) sA[w][lane + 64 * p] = e[p] * inv;
        __syncthreads();
        // feats: d4 = lane&3 (float4 of dims), grp = lane>>2
        int d4 = lane & 3, grp = lane >> 2;
        float4 f4 = {0.f, 0.f, 0.f, 0.f};
        for (int j = grp; j < N; j += 16) {
            float a = sA[w][j];
            float4 vv = *(const float4*)(v + j * HIDN + h * DHD + d4 * 4);
            f4.x += a * vv.x; f4.y += a * vv.y; f4.z += a * vv.z; f4.w += a * vv.w;
        }
#pragma unroll
        for (int off = 4; off < 64; off <<= 1) {
            f4.x += __shfl_xor(f4.x, off, 64);
            f4.y += __shfl_xor(f4.y, off, 64);
            f4.z += __shfl_xor(f4.z, off, 64);
            f4.w += __shfl_xor(f4.w, off, 64);
        }
        if (lane < 4) *(float4*)(&sUpd[h * DHD + lane * 4]) = f4;
        // coords partial
        float cx = 0.f, cy = 0.f, cz = 0.f;
#pragma unroll
        for (int p = 0; p < 6; p++) {
            int j = lane + 64 * p;
            float a = sA[w][j];
            cx += a * (cix - sCrd[j * 3]);
            cy += a * (ciy - sCrd[j * 3 + 1]);
            cz += a * (ciz - sCrd[j * 3 + 2]);
        }
        for (int off = 1; off < 64; off <<= 1) {
            cx += __shfl_xor(cx, off, 64);
            cy += __shfl_xor(cy, off, 64);
            cz += __shfl_xor(cz, off, 64);
        }
        if (lane == 0) {
            float g = gates[i * NHD + h] * (1.0f / NHD);
            sC[h][0] = g * cx; sC[h][1] = g * cy; sC[h][2] = g * cz;
        }
        __syncthreads();
    }
    if (t < 3) {
        float acc = coords[i * 3 + t];
#pragma unroll
        for (int h = 0; h < NHD; h++) acc += sC[h][t];
        out[N * HIDN + i * 3 + t] = acc;
    }
    // fused k_out: y = ef + sUpd@wo + bo, LayerNorm (waves 2,3 duplicate work)
    int c = t & 127;
    float y = ef[i * HIDN + c] + bo[c];
#pragma unroll 8
    for (int cp = 0; cp < HIDN; cp++) y += sUpd[cp] * wo[cp * HIDN + c];
    float ssum = wave_sum(y);
    if (t < 128 && (t & 63) == 0) sR2[t >> 6] = ssum;
    __syncthreads();
    float mu = (sR2[0] + sR2[1]) * (1.0f / HIDN);
    __syncthreads();
    float dv = y - mu;
    float s2 = wave_sum(dv * dv);
    if (t < 128 && (t & 63) == 0) sR2[t >> 6] = s2;
    __syncthreads();
    float var = (sR2[0] + sR2[1]) * (1.0f / HIDN);
    if (t < 128) out[i * HIDN + c] = dv * rsqrtf(var + 1e-5f) * lng[c] + lnb[c];
}

extern "C" void kernel_launch(void* const* d_in, const int* in_sizes, int n_in,
                              void* d_out, int out_size, void* d_ws, size_t ws_size,
                              hipStream_t stream) {
    const float* ef      = (const float*)d_in[0];
    const float* coords  = (const float*)d_in[1];
    const float* mask    = (const float*)d_in[2];
    const float* wq      = (const float*)d_in[3];
    const float* wk      = (const float*)d_in[4];
    const float* wv      = (const float*)d_in[5];
    const float* centers = (const float*)d_in[6];
    const float* widths  = (const float*)d_in[7];
    const float* aw1     = (const float*)d_in[8];
    const float* ab1     = (const float*)d_in[9];
    const float* aw2     = (const float*)d_in[10];
    const float* ab2     = (const float*)d_in[11];
    const float* aw3     = (const float*)d_in[12];
    const float* ab3     = (const float*)d_in[13];
    const float* gw1     = (const float*)d_in[14];
    const float* gb1     = (const float*)d_in[15];
    const float* gw2     = (const float*)d_in[16];
    const float* gb2     = (const float*)d_in[17];
    const float* wo      = (const float*)d_in[18];
    const float* bo      = (const float*)d_in[19];
    const float* lng     = (const float*)d_in[20];
    const float* lnb     = (const float*)d_in[21];
    float* ws = (float*)d_ws;
    float* v      = ws + WS_V;
    unsigned short* Qpb = (unsigned short*)(ws + WS_QPB);
    unsigned short* Kpb = (unsigned short*)(ws + WS_KPB);
    float* gates  = ws + WS_GATE;
    float* scores = ws + WS_SCORES;
    unsigned short* w2bf = (unsigned short*)(ws + WS_W2BF);
    float* out = (float*)d_out;

    k_pre<<<N, 128, 0, stream>>>(ef, wq, wk, wv, aw1, aw2, gw1, gb1, gw2, gb2, v, Qpb, Kpb, gates, w2bf);
    k_scores_mfma<<<dim3(6, N), 512, 0, stream>>>(
        coords, mask, centers, widths, aw1, ab1, ab2, aw3, ab3, Qpb, Kpb, w2bf, scores);
    k_attn2<<<N, 256, 0, stream>>>(scores, v, gates, coords, ef, wo, bo, lng, lnb, out);
}

// Round 6
// 320.374 us; speedup vs baseline: 1.5115x; 1.5115x over previous
//
#include <hip/hip_runtime.h>
#include <hip/hip_bf16.h>

#define N 384
#define HIDN 128
#define NHD 8
#define DHD 16
#define NRB 64
#define CUTF 10.0f

// ws layout (float slots)
#define WS_V 0
#define WS_QPB (WS_V + N*HIDN)                 // bf16 buffer: head-major [h][n][c]
#define WS_KPB (WS_QPB + N*NHD*HIDN/2)        // bf16 buffer: head-major [h][n][c]
#define WS_GATE (WS_KPB + N*NHD*HIDN/2)
#define WS_UPD (WS_GATE + N*NHD)
#define WS_SCORES (WS_UPD + N*HIDN)
#define WS_W2BF (WS_SCORES + NHD*N*N)         // bf16 buffer: 128*128 shorts (W2^T)

typedef short bf16x8 __attribute__((ext_vector_type(8)));
typedef float floatx4 __attribute__((ext_vector_type(4)));
#define MFMA16(a, b, c) __builtin_amdgcn_mfma_f32_16x16x32_bf16(a, b, c, 0, 0, 0)

__device__ __forceinline__ float siluf(float x) { return x / (1.0f + __expf(-x)); }
__device__ __forceinline__ float silu_fast(float x) {
    return x * __builtin_amdgcn_rcpf(1.0f + __expf(-x));
}
__device__ __forceinline__ short f2bf(float f) {
    unsigned int b = __float_as_uint(f);
    unsigned int r = (b + 0x7fffu + ((b >> 16) & 1u)) >> 16;
    return (short)r;
}
__device__ __forceinline__ float bf2f(short s) {
    return __uint_as_float(((unsigned int)(unsigned short)s) << 16);
}
// packed f32x2 -> bf16x2 (RNE), 1 instr instead of 2x5
__device__ __forceinline__ unsigned int cvt_pk_bf16(float lo, float hi) {
    unsigned int r;
    asm("v_cvt_pk_bf16_f32 %0, %1, %2" : "=v"(r) : "v"(lo), "v"(hi));
    return r;
}
__device__ __forceinline__ float wave_sum(float v) {
    for (int o = 32; o; o >>= 1) v += __shfl_down(v, o, 64);
    return v;
}

// K1: fused qkv + Qp/Kp(bf16, head-major) + gates + W2^T bf16 pre-transpose
__global__ __launch_bounds__(128) void k_pre(const float* __restrict__ ef,
    const float* __restrict__ wq, const float* __restrict__ wk, const float* __restrict__ wv,
    const float* __restrict__ aw1, const float* __restrict__ aw2,
    const float* __restrict__ gw1, const float* __restrict__ gb1,
    const float* __restrict__ gw2, const float* __restrict__ gb2,
    float* __restrict__ v, unsigned short* __restrict__ Qpb,
    unsigned short* __restrict__ Kpb, float* __restrict__ gates,
    unsigned short* __restrict__ w2bf) {
    __shared__ float sE[HIDN], sQ[HIDN], sK[HIDN], sV[HIDN];
    __shared__ float sG[NHD][2];
    int i = blockIdx.x, t = threadIdx.x;
    // blocks 0..127: also emit W2^T in bf16, row n=i, col k=t: w2bf[n][k]=aw2[k][n]
    if (i < HIDN) w2bf[(size_t)i * HIDN + t] = (unsigned short)f2bf(aw2[t * HIDN + i]);
    sE[t] = ef[i * HIDN + t];
    __syncthreads();
    float aq = 0.f, ak = 0.f, av = 0.f;
#pragma unroll 8
    for (int c = 0; c < HIDN; c++) {
        float e = sE[c];
        aq += e * wq[c * HIDN + t];
        ak += e * wk[c * HIDN + t];
        av += e * wv[c * HIDN + t];
    }
    v[i * HIDN + t] = av;
    sQ[t] = aq; sK[t] = ak; sV[t] = av;
    __syncthreads();
    for (int h = 0; h < NHD; h++) {
        float accq = 0.f, acck = 0.f;
#pragma unroll
        for (int d = 0; d < DHD; d++) {
            accq += sQ[h * DHD + d] * aw1[d * HIDN + t];
            acck += sK[h * DHD + d] * aw1[(DHD + d) * HIDN + t];
        }
        Qpb[((size_t)h * N + i) * HIDN + t] = (unsigned short)f2bf(accq);
        Kpb[((size_t)h * N + i) * HIDN + t] = (unsigned short)f2bf(acck);
        float tt = gb1[t];
#pragma unroll
        for (int d = 0; d < DHD; d++) tt += sV[h * DHD + d] * gw1[d * HIDN + t];
        float contrib = siluf(tt) * gw2[t];
        float s = wave_sum(contrib);
        if ((t & 63) == 0) sG[h][t >> 6] = s;
    }
    __syncthreads();
    if (t < NHD)
        gates[i * NHD + t] = 1.0f / (1.0f + __expf(-(sG[t][0] + sG[t][1] + gb2[0])));
}

// ---------------- K2: MFMA scores kernel ----------------
// Round-2 proven structure (launch_bounds(512,4), A2[2][4], serialized
// phases). Deltas: QPB table -> QPF registers (LDS 53888 -> 3 blocks/CU),
// head-major Kpb (dense K streams), grid (6,N) = exactly 3 residency rounds.
#define OFF_W2T 0            // 128 rows x 256B, XOR-swizzled = 32768
#define OFF_SDD 32768        // 32 f32 = 128
#define OFF_RBF 32896        // 32 rows x 128B, XOR-swizzled = 4096
#define OFF_R   36992        // 32 rows x 528B f32 = 16896
#define SMEM_SZ 53888

__global__ __launch_bounds__(512, 4) void k_scores_mfma(
    const float* __restrict__ coords, const float* __restrict__ mask,
    const float* __restrict__ centers, const float* __restrict__ widths,
    const float* __restrict__ aw1, const float* __restrict__ ab1,
    const float* __restrict__ ab2,
    const float* __restrict__ aw3, const float* __restrict__ ab3,
    const unsigned short* __restrict__ Qpb, const unsigned short* __restrict__ Kpb,
    const unsigned short* __restrict__ w2bf,
    float* __restrict__ scores) {
    __shared__ __align__(16) char smem[SMEM_SZ];
    const int t = threadIdx.x;
    const int lane = t & 63;
    const int w = t >> 6;            // wave 0..7 == head
    const int l15 = lane & 15;
    const int quad = lane >> 4;
    const int i = blockIdx.y;
    const int jb = blockIdx.x * 64;

    // ---- phase 0: stage W2^T (swizzled); per-wave register tables ----
    {
        const uint4* src = (const uint4*)w2bf;   // 2048 x 16B
        for (int idx = t; idx < 2048; idx += 512) {
            int row = idx >> 4, slot = idx & 15;
            *(uint4*)(smem + OFF_W2T + row * 256 + ((slot * 16) ^ ((row & 7) << 4))) = src[idx];
        }
    }
    // W1r B-frags in registers: wave w covers c-tile ct=w
    const int c0 = w * 16 + l15;
    bf16x8 BW1[2];
#pragma unroll
    for (int ks = 0; ks < 2; ks++) {
        bf16x8 a;
#pragma unroll
        for (int e = 0; e < 8; e++) {
            int r = ks * 32 + quad * 8 + e;
            a[e] = f2bf(aw1[(32 + r) * HIDN + c0]);
        }
        BW1[ks] = a;
    }
    // Q-proj fragments for this head (quad-dependent): QPF[f] = Qp[h][i][f*32+quad*8 ..+8]
    bf16x8 QPF[4];
#pragma unroll
    for (int f = 0; f < 4; f++)
        QPF[f] = *(const bf16x8*)(Qpb + ((size_t)w * N + i) * HIDN + f * 32 + quad * 8);
    const float b1v = ab1[c0];
    const float w1dv = aw1[96 * HIDN + c0];
    const float ab3v = ab3[w];
    float b2r[8], w3r[8];
#pragma unroll
    for (int ct = 0; ct < 8; ct++) {
        b2r[ct] = ab2[ct * 16 + l15];
        w3r[ct] = aw3[(ct * 16 + l15) * NHD + w];
    }
    const float cr = centers[lane], rwd = widths[lane];
    const float cix = coords[i * 3], ciy = coords[i * 3 + 1], ciz = coords[i * 3 + 2];
    __syncthreads();

    for (int ch = 0; ch < 2; ch++) {
        const int j0 = jb + ch * 32;
        // (a) rbf + dot. r = lane, j = w + p*8
        {
#pragma unroll
            for (int p = 0; p < 4; p++) {
                int j = w + p * 8;
                int jj = j0 + j;
                float jx = coords[jj * 3], jy = coords[jj * 3 + 1], jz = coords[jj * 3 + 2];
                float dx = cix - jx, dy = ciy - jy, dz = ciz - jz;
                float dist = sqrtf(dx * dx + dy * dy + dz * dz) + 1e-8f;
                dist = fminf(fmaxf(dist, 1e-8f), 1e8f);
                float dd = dist - cr;
                float val = (dist <= CUTF) ? __expf(-rwd * dd * dd) : 0.0f;
                *(short*)(smem + OFF_RBF + j * 128 + ((lane * 2) ^ ((j & 7) << 4))) = f2bf(val);
            }
            if (t < 32) {
                int jj = j0 + t;
                float jx = coords[jj * 3], jy = coords[jj * 3 + 1], jz = coords[jj * 3 + 2];
                float dot = fminf(fmaxf(cix * jx + ciy * jy + ciz * jz, -1e8f), 1e8f);
                *(float*)(smem + OFF_SDD + t * 4) = dot;
            }
        }
        __syncthreads();
        // (b) R = (b1 + dot*w1d) + rbf@W1r. Wave w owns c-tile ct=w, both j-tiles.
#pragma unroll
        for (int jt = 0; jt < 2; jt++) {
            int jl = jt * 16 + l15;
            int sw = (jl & 7) << 4;
            bf16x8 ra0 = *(const bf16x8*)(smem + OFF_RBF + jl * 128 + ((quad * 16) ^ sw));
            bf16x8 ra1 = *(const bf16x8*)(smem + OFF_RBF + jl * 128 + ((64 + quad * 16) ^ sw));
            floatx4 acc;
#pragma unroll
            for (int r = 0; r < 4; r++) {
                float dotv = *(const float*)(smem + OFF_SDD + (jt * 16 + quad * 4 + r) * 4);
                acc[r] = b1v + dotv * w1dv;
            }
            acc = MFMA16(ra0, BW1[0], acc);
            acc = MFMA16(ra1, BW1[1], acc);
#pragma unroll
            for (int r = 0; r < 4; r++)
                *(float*)(smem + OFF_R + (jt * 16 + quad * 4 + r) * 528 + c0 * 4) = acc[r];
        }
        __syncthreads();
        // (c) strips: head h = w; A-frags for both j-tiles (round-2 structure)
        {
            bf16x8 A2[2][4];
#pragma unroll
            for (int f = 0; f < 4; f++) {
                const int c8 = f * 32 + quad * 8;
                bf16x8 qp = QPF[f];
#pragma unroll
                for (int jt = 0; jt < 2; jt++) {
                    const int jl = jt * 16 + l15;
                    bf16x8 kp = *(const bf16x8*)(Kpb + ((size_t)w * N + j0 + jl) * HIDN + c8);
                    const char* rbase = smem + OFF_R + jl * 528 + c8 * 4;
                    float4 r0 = *(const float4*)(rbase);
                    float4 r1 = *(const float4*)(rbase + 16);
                    float xs[8] = {r0.x, r0.y, r0.z, r0.w, r1.x, r1.y, r1.z, r1.w};
                    union { unsigned int u[4]; bf16x8 v; } uu;
#pragma unroll
                    for (int e2 = 0; e2 < 4; e2++) {
                        float xa = silu_fast(bf2f(kp[2 * e2])     + bf2f(qp[2 * e2])     + xs[2 * e2]);
                        float xb = silu_fast(bf2f(kp[2 * e2 + 1]) + bf2f(qp[2 * e2 + 1]) + xs[2 * e2 + 1]);
                        uu.u[e2] = cvt_pk_bf16(xa, xb);
                    }
                    A2[jt][f] = uu.v;
                }
            }
            float part0[4] = {0.f, 0.f, 0.f, 0.f};
            float part1[4] = {0.f, 0.f, 0.f, 0.f};
#pragma unroll 2
            for (int ct = 0; ct < 8; ct++) {
                const int rw2 = ct * 16 + l15;
                const char* wb = smem + OFF_W2T + rw2 * 256;
                const int sw = (rw2 & 7) << 4;
                bf16x8 b0 = *(const bf16x8*)(wb + ((quad * 16) ^ sw));
                bf16x8 b1 = *(const bf16x8*)(wb + ((64 + quad * 16) ^ sw));
                bf16x8 b2 = *(const bf16x8*)(wb + ((128 + quad * 16) ^ sw));
                bf16x8 b3 = *(const bf16x8*)(wb + ((192 + quad * 16) ^ sw));
                float bb = b2r[ct], ww = w3r[ct];
                floatx4 acc0 = {bb, bb, bb, bb};
                acc0 = MFMA16(A2[0][0], b0, acc0);
                acc0 = MFMA16(A2[0][1], b1, acc0);
                acc0 = MFMA16(A2[0][2], b2, acc0);
                acc0 = MFMA16(A2[0][3], b3, acc0);
                floatx4 acc1 = {bb, bb, bb, bb};
                acc1 = MFMA16(A2[1][0], b0, acc1);
                acc1 = MFMA16(A2[1][1], b1, acc1);
                acc1 = MFMA16(A2[1][2], b2, acc1);
                acc1 = MFMA16(A2[1][3], b3, acc1);
#pragma unroll
                for (int r = 0; r < 4; r++) {
                    part0[r] += silu_fast(acc0[r]) * ww;
                    part1[r] += silu_fast(acc1[r]) * ww;
                }
            }
#pragma unroll
            for (int off = 1; off < 16; off <<= 1) {
#pragma unroll
                for (int r = 0; r < 4; r++) {
                    part0[r] += __shfl_xor(part0[r], off, 64);
                    part1[r] += __shfl_xor(part1[r], off, 64);
                }
            }
            if (l15 == 0) {
                const int jo = j0 + quad * 4;
                float4 mv0 = *(const float4*)(mask + (size_t)i * N + jo);
                float4 sv0;
                sv0.x = fminf(fmaxf(part0[0] + ab3v + mv0.x, -1e9f), 1e9f);
                sv0.y = fminf(fmaxf(part0[1] + ab3v + mv0.y, -1e9f), 1e9f);
                sv0.z = fminf(fmaxf(part0[2] + ab3v + mv0.z, -1e9f), 1e9f);
                sv0.w = fminf(fmaxf(part0[3] + ab3v + mv0.w, -1e9f), 1e9f);
                *(float4*)(scores + ((size_t)w * N + i) * N + jo) = sv0;
                const int jo1 = jo + 16;
                float4 mv1 = *(const float4*)(mask + (size_t)i * N + jo1);
                float4 sv1;
                sv1.x = fminf(fmaxf(part1[0] + ab3v + mv1.x, -1e9f), 1e9f);
                sv1.y = fminf(fmaxf(part1[1] + ab3v + mv1.y, -1e9f), 1e9f);
                sv1.z = fminf(fmaxf(part1[2] + ab3v + mv1.z, -1e9f), 1e9f);
                sv1.w = fminf(fmaxf(part1[3] + ab3v + mv1.w, -1e9f), 1e9f);
                *(float4*)(scores + ((size_t)w * N + i) * N + jo1) = sv1;
            }
        }
        __syncthreads();
    }
}

// K3: softmax + attn@V + coords out + fused (upd@wo + LN) epilogue.
__global__ __launch_bounds__(256) void k_attn2(
    const float* __restrict__ scores, const float* __restrict__ v,
    const float* __restrict__ gates, const float* __restrict__ coords,
    const float* __restrict__ ef, const float* __restrict__ wo,
    const float* __restrict__ bo, const float* __restrict__ lng,
    const float* __restrict__ lnb, float* __restrict__ out) {
    __shared__ float sA[4][N];
    __shared__ float sCrd[N * 3];
    __shared__ float sC[NHD][3];
    __shared__ float sUpd[HIDN];
    __shared__ float sR2[2];
    int i = blockIdx.x, t = threadIdx.x, w = t >> 6, lane = t & 63;
    for (int idx = t; idx < N * 3; idx += 256) sCrd[idx] = coords[idx];
    float cix = coords[i * 3], ciy = coords[i * 3 + 1], ciz = coords[i * 3 + 2];
    __syncthreads();
    for (int hh = 0; hh < 2; hh++) {
        int h = hh * 4 + w;
        const float* srow = scores + ((size_t)h * N + i) * N;
        float s[6];
#pragma unroll
        for (int p = 0; p < 6; p++) s[p] = srow[lane + 64 * p];
        float m = s[0];
#pragma unroll
        for (int p = 1; p < 6; p++) m = fmaxf(m, s[p]);
        for (int off = 1; off < 64; off <<= 1) m = fmaxf(m, __shfl_xor(m, off, 64));
        float e[6], sum = 0.f;
#pragma unroll
        for (int p = 0; p < 6; p++) { e[p] = __expf(s[p] - m); sum += e[p]; }
        for (int off = 1; off < 64; off <<= 1) sum += __shfl_xor(sum, off, 64);
        float inv = 1.0f / sum;
#pragma unroll
        for (int p = 0; p < 6; p++) sA[w][lane + 64 * p] = e[p] * inv;
        __syncthreads();
        // feats: d4 = lane&3 (float4 of dims), grp = lane>>2
        int d4 = lane & 3, grp = lane >> 2;
        float4 f4 = {0.f, 0.f, 0.f, 0.f};
        for (int j = grp; j < N; j += 16) {
            float a = sA[w][j];
            float4 vv = *(const float4*)(v + j * HIDN + h * DHD + d4 * 4);
            f4.x += a * vv.x; f4.y += a * vv.y; f4.z += a * vv.z; f4.w += a * vv.w;
        }
#pragma unroll
        for (int off = 4; off < 64; off <<= 1) {
            f4.x += __shfl_xor(f4.x, off, 64);
            f4.y += __shfl_xor(f4.y, off, 64);
            f4.z += __shfl_xor(f4.z, off, 64);
            f4.w += __shfl_xor(f4.w, off, 64);
        }
        if (lane < 4) *(float4*)(&sUpd[h * DHD + lane * 4]) = f4;
        // coords partial
        float cx = 0.f, cy = 0.f, cz = 0.f;
#pragma unroll
        for (int p = 0; p < 6; p++) {
            int j = lane + 64 * p;
            float a = sA[w][j];
            cx += a * (cix - sCrd[j * 3]);
            cy += a * (ciy - sCrd[j * 3 + 1]);
            cz += a * (ciz - sCrd[j * 3 + 2]);
        }
        for (int off = 1; off < 64; off <<= 1) {
            cx += __shfl_xor(cx, off, 64);
            cy += __shfl_xor(cy, off, 64);
            cz += __shfl_xor(cz, off, 64);
        }
        if (lane == 0) {
            float g = gates[i * NHD + h] * (1.0f / NHD);
            sC[h][0] = g * cx; sC[h][1] = g * cy; sC[h][2] = g * cz;
        }
        __syncthreads();
    }
    if (t < 3) {
        float acc = coords[i * 3 + t];
#pragma unroll
        for (int h = 0; h < NHD; h++) acc += sC[h][t];
        out[N * HIDN + i * 3 + t] = acc;
    }
    // fused k_out: y = ef + sUpd@wo + bo, LayerNorm (waves 2,3 duplicate work)
    int c = t & 127;
    float y = ef[i * HIDN + c] + bo[c];
#pragma unroll 8
    for (int cp = 0; cp < HIDN; cp++) y += sUpd[cp] * wo[cp * HIDN + c];
    float ssum = wave_sum(y);
    if (t < 128 && (t & 63) == 0) sR2[t >> 6] = ssum;
    __syncthreads();
    float mu = (sR2[0] + sR2[1]) * (1.0f / HIDN);
    __syncthreads();
    float dv = y - mu;
    float s2 = wave_sum(dv * dv);
    if (t < 128 && (t & 63) == 0) sR2[t >> 6] = s2;
    __syncthreads();
    float var = (sR2[0] + sR2[1]) * (1.0f / HIDN);
    if (t < 128) out[i * HIDN + c] = dv * rsqrtf(var + 1e-5f) * lng[c] + lnb[c];
}

extern "C" void kernel_launch(void* const* d_in, const int* in_sizes, int n_in,
                              void* d_out, int out_size, void* d_ws, size_t ws_size,
                              hipStream_t stream) {
    const float* ef      = (const float*)d_in[0];
    const float* coords  = (const float*)d_in[1];
    const float* mask    = (const float*)d_in[2];
    const float* wq      = (const float*)d_in[3];
    const float* wk      = (const float*)d_in[4];
    const float* wv      = (const float*)d_in[5];
    const float* centers = (const float*)d_in[6];
    const float* widths  = (const float*)d_in[7];
    const float* aw1     = (const float*)d_in[8];
    const float* ab1     = (const float*)d_in[9];
    const float* aw2     = (const float*)d_in[10];
    const float* ab2     = (const float*)d_in[11];
    const float* aw3     = (const float*)d_in[12];
    const float* ab3     = (const float*)d_in[13];
    const float* gw1     = (const float*)d_in[14];
    const float* gb1     = (const float*)d_in[15];
    const float* gw2     = (const float*)d_in[16];
    const float* gb2     = (const float*)d_in[17];
    const float* wo      = (const float*)d_in[18];
    const float* bo      = (const float*)d_in[19];
    const float* lng     = (const float*)d_in[20];
    const float* lnb     = (const float*)d_in[21];
    float* ws = (float*)d_ws;
    float* v      = ws + WS_V;
    unsigned short* Qpb = (unsigned short*)(ws + WS_QPB);
    unsigned short* Kpb = (unsigned short*)(ws + WS_KPB);
    float* gates  = ws + WS_GATE;
    float* scores = ws + WS_SCORES;
    unsigned short* w2bf = (unsigned short*)(ws + WS_W2BF);
    float* out = (float*)d_out;

    k_pre<<<N, 128, 0, stream>>>(ef, wq, wk, wv, aw1, aw2, gw1, gb1, gw2, gb2, v, Qpb, Kpb, gates, w2bf);
    k_scores_mfma<<<dim3(6, N), 512, 0, stream>>>(
        coords, mask, centers, widths, aw1, ab1, ab2, aw3, ab3, Qpb, Kpb, w2bf, scores);
    k_attn2<<<N, 256, 0, stream>>>(scores, v, gates, coords, ef, wo, bo, lng, lnb, out);
}

// Round 7
// 310.048 us; speedup vs baseline: 1.5618x; 1.0333x over previous
//
#include <hip/hip_runtime.h>
#include <hip/hip_bf16.h>

#define N 384
#define HIDN 128
#define NHD 8
#define DHD 16
#define NRB 64
#define CUTF 10.0f

// ws layout (float slots)
#define WS_V 0
#define WS_QPB (WS_V + N*HIDN)                 // bf16 buffer: head-major [h][n][c]
#define WS_KPB (WS_QPB + N*NHD*HIDN/2)        // bf16 buffer: head-major [h][n][c]
#define WS_GATE (WS_KPB + N*NHD*HIDN/2)
#define WS_UPD (WS_GATE + N*NHD)
#define WS_SCORES (WS_UPD + N*HIDN)
#define WS_W2BF (WS_SCORES + NHD*N*N)         // bf16 buffer: 128*128 shorts (W2^T)

typedef short bf16x8 __attribute__((ext_vector_type(8)));
typedef float floatx4 __attribute__((ext_vector_type(4)));
#define MFMA16(a, b, c) __builtin_amdgcn_mfma_f32_16x16x32_bf16(a, b, c, 0, 0, 0)

__device__ __forceinline__ float siluf(float x) { return x / (1.0f + __expf(-x)); }
__device__ __forceinline__ float silu_fast(float x) {
    return x * __builtin_amdgcn_rcpf(1.0f + __expf(-x));
}
__device__ __forceinline__ short f2bf(float f) {
    unsigned int b = __float_as_uint(f);
    unsigned int r = (b + 0x7fffu + ((b >> 16) & 1u)) >> 16;
    return (short)r;
}
__device__ __forceinline__ float bf2f(short s) {
    return __uint_as_float(((unsigned int)(unsigned short)s) << 16);
}
// packed f32x2 -> bf16x2 (RNE), 1 instr instead of 2x5
__device__ __forceinline__ unsigned int cvt_pk_bf16(float lo, float hi) {
    unsigned int r;
    asm("v_cvt_pk_bf16_f32 %0, %1, %2" : "=v"(r) : "v"(lo), "v"(hi));
    return r;
}
__device__ __forceinline__ float wave_sum(float v) {
    for (int o = 32; o; o >>= 1) v += __shfl_down(v, o, 64);
    return v;
}

// K1: fused qkv + Qp/Kp(bf16, head-major) + gates + W2^T bf16 pre-transpose
__global__ __launch_bounds__(128) void k_pre(const float* __restrict__ ef,
    const float* __restrict__ wq, const float* __restrict__ wk, const float* __restrict__ wv,
    const float* __restrict__ aw1, const float* __restrict__ aw2,
    const float* __restrict__ gw1, const float* __restrict__ gb1,
    const float* __restrict__ gw2, const float* __restrict__ gb2,
    float* __restrict__ v, unsigned short* __restrict__ Qpb,
    unsigned short* __restrict__ Kpb, float* __restrict__ gates,
    unsigned short* __restrict__ w2bf) {
    __shared__ float sE[HIDN], sQ[HIDN], sK[HIDN], sV[HIDN];
    __shared__ float sG[NHD][2];
    int i = blockIdx.x, t = threadIdx.x;
    // blocks 0..127: also emit W2^T in bf16, row n=i, col k=t: w2bf[n][k]=aw2[k][n]
    if (i < HIDN) w2bf[(size_t)i * HIDN + t] = (unsigned short)f2bf(aw2[t * HIDN + i]);
    sE[t] = ef[i * HIDN + t];
    __syncthreads();
    float aq = 0.f, ak = 0.f, av = 0.f;
#pragma unroll 8
    for (int c = 0; c < HIDN; c++) {
        float e = sE[c];
        aq += e * wq[c * HIDN + t];
        ak += e * wk[c * HIDN + t];
        av += e * wv[c * HIDN + t];
    }
    v[i * HIDN + t] = av;
    sQ[t] = aq; sK[t] = ak; sV[t] = av;
    __syncthreads();
    for (int h = 0; h < NHD; h++) {
        float accq = 0.f, acck = 0.f;
#pragma unroll
        for (int d = 0; d < DHD; d++) {
            accq += sQ[h * DHD + d] * aw1[d * HIDN + t];
            acck += sK[h * DHD + d] * aw1[(DHD + d) * HIDN + t];
        }
        Qpb[((size_t)h * N + i) * HIDN + t] = (unsigned short)f2bf(accq);
        Kpb[((size_t)h * N + i) * HIDN + t] = (unsigned short)f2bf(acck);
        float tt = gb1[t];
#pragma unroll
        for (int d = 0; d < DHD; d++) tt += sV[h * DHD + d] * gw1[d * HIDN + t];
        float contrib = siluf(tt) * gw2[t];
        float s = wave_sum(contrib);
        if ((t & 63) == 0) sG[h][t >> 6] = s;
    }
    __syncthreads();
    if (t < NHD)
        gates[i * NHD + t] = 1.0f / (1.0f + __expf(-(sG[t][0] + sG[t][1] + gb2[0])));
}

// ---------------- K2: MFMA scores kernel ----------------
// launch_bounds(512,3): VGPR cap ~80-85 = 6 waves/SIMD = 3 blocks/CU,
// matching LDS 53888's 3-block limit. Per-thread state trimmed to fit:
// jt-split phase (c) (A[4]), b2+w3 packed as bf16 pairs (8 regs).
#define OFF_W2T 0            // 128 rows x 256B, XOR-swizzled = 32768
#define OFF_SDD 32768        // 32 f32 = 128
#define OFF_RBF 32896        // 32 rows x 128B, XOR-swizzled = 4096
#define OFF_R   36992        // 32 rows x 528B f32 = 16896
#define SMEM_SZ 53888

__global__ __launch_bounds__(512, 3) void k_scores_mfma(
    const float* __restrict__ coords, const float* __restrict__ mask,
    const float* __restrict__ centers, const float* __restrict__ widths,
    const float* __restrict__ aw1, const float* __restrict__ ab1,
    const float* __restrict__ ab2,
    const float* __restrict__ aw3, const float* __restrict__ ab3,
    const unsigned short* __restrict__ Qpb, const unsigned short* __restrict__ Kpb,
    const unsigned short* __restrict__ w2bf,
    float* __restrict__ scores) {
    __shared__ __align__(16) char smem[SMEM_SZ];
    const int t = threadIdx.x;
    const int lane = t & 63;
    const int w = t >> 6;            // wave 0..7 == head
    const int l15 = lane & 15;
    const int quad = lane >> 4;
    const int i = blockIdx.y;
    const int jb = blockIdx.x * 64;

    // ---- phase 0: stage W2^T (swizzled); per-wave register tables ----
    {
        const uint4* src = (const uint4*)w2bf;   // 2048 x 16B
        for (int idx = t; idx < 2048; idx += 512) {
            int row = idx >> 4, slot = idx & 15;
            *(uint4*)(smem + OFF_W2T + row * 256 + ((slot * 16) ^ ((row & 7) << 4))) = src[idx];
        }
    }
    // W1r B-frags in registers: wave w covers c-tile ct=w
    const int c0 = w * 16 + l15;
    bf16x8 BW1[2];
#pragma unroll
    for (int ks = 0; ks < 2; ks++) {
        bf16x8 a;
#pragma unroll
        for (int e = 0; e < 8; e++) {
            int r = ks * 32 + quad * 8 + e;
            a[e] = f2bf(aw1[(32 + r) * HIDN + c0]);
        }
        BW1[ks] = a;
    }
    // Q-proj fragments for this head (quad-dependent): QPF[f] = Qp[h][i][f*32+quad*8 ..+8]
    bf16x8 QPF[4];
#pragma unroll
    for (int f = 0; f < 4; f++)
        QPF[f] = *(const bf16x8*)(Qpb + ((size_t)w * N + i) * HIDN + f * 32 + quad * 8);
    const float b1v = ab1[c0];
    const float w1dv = aw1[96 * HIDN + c0];
    const float ab3v = ab3[w];
    // b2 + w3 packed as bf16 pairs: lo = b2[ct*16+l15], hi = w3[ct*16+l15][w]
    unsigned int b2w3[8];
#pragma unroll
    for (int ct = 0; ct < 8; ct++) {
        unsigned int lo = (unsigned short)f2bf(ab2[ct * 16 + l15]);
        unsigned int hi = (unsigned short)f2bf(aw3[(ct * 16 + l15) * NHD + w]);
        b2w3[ct] = (hi << 16) | lo;
    }
    const float cr = centers[lane], rwd = widths[lane];
    const float cix = coords[i * 3], ciy = coords[i * 3 + 1], ciz = coords[i * 3 + 2];
    __syncthreads();

    for (int ch = 0; ch < 2; ch++) {
        const int j0 = jb + ch * 32;
        // (a) rbf + dot. r = lane, j = w + p*8
        {
#pragma unroll
            for (int p = 0; p < 4; p++) {
                int j = w + p * 8;
                int jj = j0 + j;
                float jx = coords[jj * 3], jy = coords[jj * 3 + 1], jz = coords[jj * 3 + 2];
                float dx = cix - jx, dy = ciy - jy, dz = ciz - jz;
                float dist = sqrtf(dx * dx + dy * dy + dz * dz) + 1e-8f;
                dist = fminf(fmaxf(dist, 1e-8f), 1e8f);
                float dd = dist - cr;
                float val = (dist <= CUTF) ? __expf(-rwd * dd * dd) : 0.0f;
                *(short*)(smem + OFF_RBF + j * 128 + ((lane * 2) ^ ((j & 7) << 4))) = f2bf(val);
            }
            if (t < 32) {
                int jj = j0 + t;
                float jx = coords[jj * 3], jy = coords[jj * 3 + 1], jz = coords[jj * 3 + 2];
                float dot = fminf(fmaxf(cix * jx + ciy * jy + ciz * jz, -1e8f), 1e8f);
                *(float*)(smem + OFF_SDD + t * 4) = dot;
            }
        }
        __syncthreads();
        // (b) R = (b1 + dot*w1d) + rbf@W1r. Wave w owns c-tile ct=w, both j-tiles.
#pragma unroll
        for (int jt = 0; jt < 2; jt++) {
            int jl = jt * 16 + l15;
            int sw = (jl & 7) << 4;
            bf16x8 ra0 = *(const bf16x8*)(smem + OFF_RBF + jl * 128 + ((quad * 16) ^ sw));
            bf16x8 ra1 = *(const bf16x8*)(smem + OFF_RBF + jl * 128 + ((64 + quad * 16) ^ sw));
            floatx4 acc;
#pragma unroll
            for (int r = 0; r < 4; r++) {
                float dotv = *(const float*)(smem + OFF_SDD + (jt * 16 + quad * 4 + r) * 4);
                acc[r] = b1v + dotv * w1dv;
            }
            acc = MFMA16(ra0, BW1[0], acc);
            acc = MFMA16(ra1, BW1[1], acc);
#pragma unroll
            for (int r = 0; r < 4; r++)
                *(float*)(smem + OFF_R + (jt * 16 + quad * 4 + r) * 528 + c0 * 4) = acc[r];
        }
        __syncthreads();
        // (c) strips: head h = w; jt-split keeps A at 4 frags (16 regs)
#pragma unroll
        for (int jt = 0; jt < 2; jt++) {
            const int jl = jt * 16 + l15;
            bf16x8 A[4];
#pragma unroll
            for (int f = 0; f < 4; f++) {
                const int c8 = f * 32 + quad * 8;
                bf16x8 kp = *(const bf16x8*)(Kpb + ((size_t)w * N + j0 + jl) * HIDN + c8);
                bf16x8 qp = QPF[f];
                const char* rbase = smem + OFF_R + jl * 528 + c8 * 4;
                float4 r0 = *(const float4*)(rbase);
                float4 r1 = *(const float4*)(rbase + 16);
                float xs[8] = {r0.x, r0.y, r0.z, r0.w, r1.x, r1.y, r1.z, r1.w};
                union { unsigned int u[4]; bf16x8 v; } uu;
#pragma unroll
                for (int e2 = 0; e2 < 4; e2++) {
                    float xa = silu_fast(bf2f(kp[2 * e2])     + bf2f(qp[2 * e2])     + xs[2 * e2]);
                    float xb = silu_fast(bf2f(kp[2 * e2 + 1]) + bf2f(qp[2 * e2 + 1]) + xs[2 * e2 + 1]);
                    uu.u[e2] = cvt_pk_bf16(xa, xb);
                }
                A[f] = uu.v;
            }
            float part[4] = {0.f, 0.f, 0.f, 0.f};
#pragma unroll 2
            for (int ct = 0; ct < 8; ct++) {
                const int rw2 = ct * 16 + l15;
                const char* wb = smem + OFF_W2T + rw2 * 256;
                const int sw = (rw2 & 7) << 4;
                bf16x8 b0 = *(const bf16x8*)(wb + ((quad * 16) ^ sw));
                bf16x8 b1 = *(const bf16x8*)(wb + ((64 + quad * 16) ^ sw));
                bf16x8 b2 = *(const bf16x8*)(wb + ((128 + quad * 16) ^ sw));
                bf16x8 b3 = *(const bf16x8*)(wb + ((192 + quad * 16) ^ sw));
                unsigned int pk = b2w3[ct];
                float bb = bf2f((short)(pk & 0xffffu));
                float ww = bf2f((short)(pk >> 16));
                floatx4 acc = {bb, bb, bb, bb};
                acc = MFMA16(A[0], b0, acc);
                acc = MFMA16(A[1], b1, acc);
                acc = MFMA16(A[2], b2, acc);
                acc = MFMA16(A[3], b3, acc);
#pragma unroll
                for (int r = 0; r < 4; r++)
                    part[r] += silu_fast(acc[r]) * ww;
            }
#pragma unroll
            for (int off = 1; off < 16; off <<= 1) {
#pragma unroll
                for (int r = 0; r < 4; r++)
                    part[r] += __shfl_xor(part[r], off, 64);
            }
            if (l15 == 0) {
                const int jo = j0 + jt * 16 + quad * 4;
                float4 mv = *(const float4*)(mask + (size_t)i * N + jo);
                float4 sv;
                sv.x = fminf(fmaxf(part[0] + ab3v + mv.x, -1e9f), 1e9f);
                sv.y = fminf(fmaxf(part[1] + ab3v + mv.y, -1e9f), 1e9f);
                sv.z = fminf(fmaxf(part[2] + ab3v + mv.z, -1e9f), 1e9f);
                sv.w = fminf(fmaxf(part[3] + ab3v + mv.w, -1e9f), 1e9f);
                *(float4*)(scores + ((size_t)w * N + i) * N + jo) = sv;
            }
        }
        __syncthreads();
    }
}

// K3: softmax + attn@V + coords out + fused (upd@wo + LN) epilogue.
__global__ __launch_bounds__(256) void k_attn2(
    const float* __restrict__ scores, const float* __restrict__ v,
    const float* __restrict__ gates, const float* __restrict__ coords,
    const float* __restrict__ ef, const float* __restrict__ wo,
    const float* __restrict__ bo, const float* __restrict__ lng,
    const float* __restrict__ lnb, float* __restrict__ out) {
    __shared__ float sA[4][N];
    __shared__ float sCrd[N * 3];
    __shared__ float sC[NHD][3];
    __shared__ float sUpd[HIDN];
    __shared__ float sR2[2];
    int i = blockIdx.x, t = threadIdx.x, w = t >> 6, lane = t & 63;
    for (int idx = t; idx < N * 3; idx += 256) sCrd[idx] = coords[idx];
    float cix = coords[i * 3], ciy = coords[i * 3 + 1], ciz = coords[i * 3 + 2];
    __syncthreads();
    for (int hh = 0; hh < 2; hh++) {
        int h = hh * 4 + w;
        const float* srow = scores + ((size_t)h * N + i) * N;
        float s[6];
#pragma unroll
        for (int p = 0; p < 6; p++) s[p] = srow[lane + 64 * p];
        float m = s[0];
#pragma unroll
        for (int p = 1; p < 6; p++) m = fmaxf(m, s[p]);
        for (int off = 1; off < 64; off <<= 1) m = fmaxf(m, __shfl_xor(m, off, 64));
        float e[6], sum = 0.f;
#pragma unroll
        for (int p = 0; p < 6; p++) { e[p] = __expf(s[p] - m); sum += e[p]; }
        for (int off = 1; off < 64; off <<= 1) sum += __shfl_xor(sum, off, 64);
        float inv = 1.0f / sum;
#pragma unroll
        for (int p = 0; p < 6; p++) sA[w][lane + 64 * p] = e[p] * inv;
        __syncthreads();
        // feats: d4 = lane&3 (float4 of dims), grp = lane>>2
        int d4 = lane & 3, grp = lane >> 2;
        float4 f4 = {0.f, 0.f, 0.f, 0.f};
        for (int j = grp; j < N; j += 16) {
            float a = sA[w][j];
            float4 vv = *(const float4*)(v + j * HIDN + h * DHD + d4 * 4);
            f4.x += a * vv.x; f4.y += a * vv.y; f4.z += a * vv.z; f4.w += a * vv.w;
        }
#pragma unroll
        for (int off = 4; off < 64; off <<= 1) {
            f4.x += __shfl_xor(f4.x, off, 64);
            f4.y += __shfl_xor(f4.y, off, 64);
            f4.z += __shfl_xor(f4.z, off, 64);
            f4.w += __shfl_xor(f4.w, off, 64);
        }
        if (lane < 4) *(float4*)(&sUpd[h * DHD + lane * 4]) = f4;
        // coords partial
        float cx = 0.f, cy = 0.f, cz = 0.f;
#pragma unroll
        for (int p = 0; p < 6; p++) {
            int j = lane + 64 * p;
            float a = sA[w][j];
            cx += a * (cix - sCrd[j * 3]);
            cy += a * (ciy - sCrd[j * 3 + 1]);
            cz += a * (ciz - sCrd[j * 3 + 2]);
        }
        for (int off = 1; off < 64; off <<= 1) {
            cx += __shfl_xor(cx, off, 64);
            cy += __shfl_xor(cy, off, 64);
            cz += __shfl_xor(cz, off, 64);
        }
        if (lane == 0) {
            float g = gates[i * NHD + h] * (1.0f / NHD);
            sC[h][0] = g * cx; sC[h][1] = g * cy; sC[h][2] = g * cz;
        }
        __syncthreads();
    }
    if (t < 3) {
        float acc = coords[i * 3 + t];
#pragma unroll
        for (int h = 0; h < NHD; h++) acc += sC[h][t];
        out[N * HIDN + i * 3 + t] = acc;
    }
    // fused k_out: y = ef + sUpd@wo + bo, LayerNorm (waves 2,3 duplicate work)
    int c = t & 127;
    float y = ef[i * HIDN + c] + bo[c];
#pragma unroll 8
    for (int cp = 0; cp < HIDN; cp++) y += sUpd[cp] * wo[cp * HIDN + c];
    float ssum = wave_sum(y);
    if (t < 128 && (t & 63) == 0) sR2[t >> 6] = ssum;
    __syncthreads();
    float mu = (sR2[0] + sR2[1]) * (1.0f / HIDN);
    __syncthreads();
    float dv = y - mu;
    float s2 = wave_sum(dv * dv);
    if (t < 128 && (t & 63) == 0) sR2[t >> 6] = s2;
    __syncthreads();
    float var = (sR2[0] + sR2[1]) * (1.0f / HIDN);
    if (t < 128) out[i * HIDN + c] = dv * rsqrtf(var + 1e-5f) * lng[c] + lnb[c];
}

extern "C" void kernel_launch(void* const* d_in, const int* in_sizes, int n_in,
                              void* d_out, int out_size, void* d_ws, size_t ws_size,
                              hipStream_t stream) {
    const float* ef      = (const float*)d_in[0];
    const float* coords  = (const float*)d_in[1];
    const float* mask    = (const float*)d_in[2];
    const float* wq      = (const float*)d_in[3];
    const float* wk      = (const float*)d_in[4];
    const float* wv      = (const float*)d_in[5];
    const float* centers = (const float*)d_in[6];
    const float* widths  = (const float*)d_in[7];
    const float* aw1     = (const float*)d_in[8];
    const float* ab1     = (const float*)d_in[9];
    const float* aw2     = (const float*)d_in[10];
    const float* ab2     = (const float*)d_in[11];
    const float* aw3     = (const float*)d_in[12];
    const float* ab3     = (const float*)d_in[13];
    const float* gw1     = (const float*)d_in[14];
    const float* gb1     = (const float*)d_in[15];
    const float* gw2     = (const float*)d_in[16];
    const float* gb2     = (const float*)d_in[17];
    const float* wo      = (const float*)d_in[18];
    const float* bo      = (const float*)d_in[19];
    const float* lng     = (const float*)d_in[20];
    const float* lnb     = (const float*)d_in[21];
    float* ws = (float*)d_ws;
    float* v      = ws + WS_V;
    unsigned short* Qpb = (unsigned short*)(ws + WS_QPB);
    unsigned short* Kpb = (unsigned short*)(ws + WS_KPB);
    float* gates  = ws + WS_GATE;
    float* scores = ws + WS_SCORES;
    unsigned short* w2bf = (unsigned short*)(ws + WS_W2BF);
    float* out = (float*)d_out;

    k_pre<<<N, 128, 0, stream>>>(ef, wq, wk, wv, aw1, aw2, gw1, gb1, gw2, gb2, v, Qpb, Kpb, gates, w2bf);
    k_scores_mfma<<<dim3(6, N), 512, 0, stream>>>(
        coords, mask, centers, widths, aw1, ab1, ab2, aw3, ab3, Qpb, Kpb, w2bf, scores);
    k_attn2<<<N, 256, 0, stream>>>(scores, v, gates, coords, ef, wo, bo, lng, lnb, out);
}

// Round 8
// 253.390 us; speedup vs baseline: 1.9110x; 1.2236x over previous
//
#include <hip/hip_runtime.h>
#include <hip/hip_bf16.h>

#define N 384
#define HIDN 128
#define NHD 8
#define DHD 16
#define NRB 64
#define CUTF 10.0f

// ws layout (float slots)
#define WS_V 0
#define WS_QPB (WS_V + N*HIDN)                 // bf16 buffer: head-major [h][n][c]
#define WS_KPB (WS_QPB + N*NHD*HIDN/2)        // bf16 buffer: head-major [h][n][c]
#define WS_GATE (WS_KPB + N*NHD*HIDN/2)
#define WS_UPD (WS_GATE + N*NHD)
#define WS_SCORES (WS_UPD + N*HIDN)
#define WS_W2BF (WS_SCORES + NHD*N*N)         // bf16 buffer: 128*128 shorts (W2^T)

typedef short bf16x8 __attribute__((ext_vector_type(8)));
typedef float floatx4 __attribute__((ext_vector_type(4)));
#define MFMA16(a, b, c) __builtin_amdgcn_mfma_f32_16x16x32_bf16(a, b, c, 0, 0, 0)

__device__ __forceinline__ float siluf(float x) { return x / (1.0f + __expf(-x)); }
__device__ __forceinline__ float silu_fast(float x) {
    return x * __builtin_amdgcn_rcpf(1.0f + __expf(-x));
}
__device__ __forceinline__ short f2bf(float f) {
    unsigned int b = __float_as_uint(f);
    unsigned int r = (b + 0x7fffu + ((b >> 16) & 1u)) >> 16;
    return (short)r;
}
__device__ __forceinline__ float bf2f(short s) {
    return __uint_as_float(((unsigned int)(unsigned short)s) << 16);
}
// packed f32x2 -> bf16x2 (RNE), 1 instr instead of 2x5
__device__ __forceinline__ unsigned int cvt_pk_bf16(float lo, float hi) {
    unsigned int r;
    asm("v_cvt_pk_bf16_f32 %0, %1, %2" : "=v"(r) : "v"(lo), "v"(hi));
    return r;
}
__device__ __forceinline__ float wave_sum(float v) {
    for (int o = 32; o; o >>= 1) v += __shfl_down(v, o, 64);
    return v;
}

// K1: fused qkv + Qp/Kp(bf16, head-major) + gates + W2^T bf16 pre-transpose
__global__ __launch_bounds__(128) void k_pre(const float* __restrict__ ef,
    const float* __restrict__ wq, const float* __restrict__ wk, const float* __restrict__ wv,
    const float* __restrict__ aw1, const float* __restrict__ aw2,
    const float* __restrict__ gw1, const float* __restrict__ gb1,
    const float* __restrict__ gw2, const float* __restrict__ gb2,
    float* __restrict__ v, unsigned short* __restrict__ Qpb,
    unsigned short* __restrict__ Kpb, float* __restrict__ gates,
    unsigned short* __restrict__ w2bf) {
    __shared__ float sE[HIDN], sQ[HIDN], sK[HIDN], sV[HIDN];
    __shared__ float sG[NHD][2];
    int i = blockIdx.x, t = threadIdx.x;
    // blocks 0..127: also emit W2^T in bf16, row n=i, col k=t: w2bf[n][k]=aw2[k][n]
    if (i < HIDN) w2bf[(size_t)i * HIDN + t] = (unsigned short)f2bf(aw2[t * HIDN + i]);
    sE[t] = ef[i * HIDN + t];
    __syncthreads();
    float aq = 0.f, ak = 0.f, av = 0.f;
#pragma unroll 8
    for (int c = 0; c < HIDN; c++) {
        float e = sE[c];
        aq += e * wq[c * HIDN + t];
        ak += e * wk[c * HIDN + t];
        av += e * wv[c * HIDN + t];
    }
    v[i * HIDN + t] = av;
    sQ[t] = aq; sK[t] = ak; sV[t] = av;
    __syncthreads();
    for (int h = 0; h < NHD; h++) {
        float accq = 0.f, acck = 0.f;
#pragma unroll
        for (int d = 0; d < DHD; d++) {
            accq += sQ[h * DHD + d] * aw1[d * HIDN + t];
            acck += sK[h * DHD + d] * aw1[(DHD + d) * HIDN + t];
        }
        Qpb[((size_t)h * N + i) * HIDN + t] = (unsigned short)f2bf(accq);
        Kpb[((size_t)h * N + i) * HIDN + t] = (unsigned short)f2bf(acck);
        float tt = gb1[t];
#pragma unroll
        for (int d = 0; d < DHD; d++) tt += sV[h * DHD + d] * gw1[d * HIDN + t];
        float contrib = siluf(tt) * gw2[t];
        float s = wave_sum(contrib);
        if ((t & 63) == 0) sG[h][t >> 6] = s;
    }
    __syncthreads();
    if (t < NHD)
        gates[i * NHD + t] = 1.0f / (1.0f + __expf(-(sG[t][0] + sG[t][1] + gb2[0])));
}

// ---------------- K2: MFMA scores kernel ----------------
// Target: VGPR <= 64 (HW granule) + LDS 52096 (3 blocks/CU) + no spill.
// All per-thread tables in LDS (QPB, b2w3); R buffer per-jt (16 rows);
// per chunk: a; bar; {b(jt); bar; c(jt); bar} x2.  Grid (4,N): 96-j
// blocks, 3 chunks, 1536 blocks = exactly 2 rounds at 3 blocks/CU.
#define OFF_W2T  0            // 128 rows x 256B, XOR-swizzled = 32768
#define OFF_QPB  32768        // 8x128 bf16 = 2048
#define OFF_SDD  34816        // 32 f32 = 128
#define OFF_RBF  34944        // 32 rows x 128B, XOR-swizzled = 4096
#define OFF_R    39040        // 16 rows x 528B f32 = 8448
#define OFF_B2W3 47488        // 128 x 9 u32 (stride-9 pad) = 4608
#define SMEM_SZ  52096

__global__ __launch_bounds__(512, 4) void k_scores_mfma(
    const float* __restrict__ coords, const float* __restrict__ mask,
    const float* __restrict__ centers, const float* __restrict__ widths,
    const float* __restrict__ aw1, const float* __restrict__ ab1,
    const float* __restrict__ ab2,
    const float* __restrict__ aw3, const float* __restrict__ ab3,
    const unsigned short* __restrict__ Qpb, const unsigned short* __restrict__ Kpb,
    const unsigned short* __restrict__ w2bf,
    float* __restrict__ scores) {
    __shared__ __align__(16) char smem[SMEM_SZ];
    const int t = threadIdx.x;
    const int lane = t & 63;
    const int w = t >> 6;            // wave 0..7 == head
    const int l15 = lane & 15;
    const int quad = lane >> 4;
    const int i = blockIdx.y;
    const int jb = blockIdx.x * 96;

    // ---- phase 0: stage W2^T (swizzled) + QPB + b2w3 table ----
    {
        const uint4* src = (const uint4*)w2bf;   // 2048 x 16B
        for (int idx = t; idx < 2048; idx += 512) {
            int row = idx >> 4, slot = idx & 15;
            *(uint4*)(smem + OFF_W2T + row * 256 + ((slot * 16) ^ ((row & 7) << 4))) = src[idx];
        }
    }
    if (t < 128)
        ((uint4*)(smem + OFF_QPB))[t] = ((const uint4*)(Qpb + (size_t)i * NHD * HIDN))[t];
    for (int idx = t; idx < HIDN * NHD; idx += 512) {
        int c = idx >> 3, h = idx & 7;
        unsigned int lo = (unsigned short)f2bf(ab2[c]);
        unsigned int hi = (unsigned short)f2bf(aw3[c * NHD + h]);
        *(unsigned int*)(smem + OFF_B2W3 + (c * 9 + h) * 4) = (hi << 16) | lo;
    }
    // W1r B-frags in registers: wave w covers c-tile ct=w
    const int c0 = w * 16 + l15;
    bf16x8 BW1[2];
#pragma unroll
    for (int ks = 0; ks < 2; ks++) {
        bf16x8 a;
#pragma unroll
        for (int e = 0; e < 8; e++) {
            int r = ks * 32 + quad * 8 + e;
            a[e] = f2bf(aw1[(32 + r) * HIDN + c0]);
        }
        BW1[ks] = a;
    }
    const float b1v = ab1[c0];
    const float w1dv = aw1[96 * HIDN + c0];
    const float ab3v = ab3[w];
    const float cr = centers[lane], rwd = widths[lane];
    const float cix = coords[i * 3], ciy = coords[i * 3 + 1], ciz = coords[i * 3 + 2];
    __syncthreads();

    for (int ch = 0; ch < 3; ch++) {
        const int j0 = jb + ch * 32;
        // (a) rbf + dot. r = lane, j = w + p*8
        {
#pragma unroll
            for (int p = 0; p < 4; p++) {
                int j = w + p * 8;
                int jj = j0 + j;
                float jx = coords[jj * 3], jy = coords[jj * 3 + 1], jz = coords[jj * 3 + 2];
                float dx = cix - jx, dy = ciy - jy, dz = ciz - jz;
                float dist = sqrtf(dx * dx + dy * dy + dz * dz) + 1e-8f;
                dist = fminf(fmaxf(dist, 1e-8f), 1e8f);
                float dd = dist - cr;
                float val = (dist <= CUTF) ? __expf(-rwd * dd * dd) : 0.0f;
                *(short*)(smem + OFF_RBF + j * 128 + ((lane * 2) ^ ((j & 7) << 4))) = f2bf(val);
            }
            if (t < 32) {
                int jj = j0 + t;
                float jx = coords[jj * 3], jy = coords[jj * 3 + 1], jz = coords[jj * 3 + 2];
                float dot = fminf(fmaxf(cix * jx + ciy * jy + ciz * jz, -1e8f), 1e8f);
                *(float*)(smem + OFF_SDD + t * 4) = dot;
            }
        }
        __syncthreads();
#pragma unroll
        for (int jt = 0; jt < 2; jt++) {
            // (b) R16 = (b1 + dot*w1d) + rbf@W1r for this jt's 16 rows
            {
                int jl = jt * 16 + l15;
                int sw = (jl & 7) << 4;
                bf16x8 ra0 = *(const bf16x8*)(smem + OFF_RBF + jl * 128 + ((quad * 16) ^ sw));
                bf16x8 ra1 = *(const bf16x8*)(smem + OFF_RBF + jl * 128 + ((64 + quad * 16) ^ sw));
                floatx4 acc;
#pragma unroll
                for (int r = 0; r < 4; r++) {
                    float dotv = *(const float*)(smem + OFF_SDD + (jt * 16 + quad * 4 + r) * 4);
                    acc[r] = b1v + dotv * w1dv;
                }
                acc = MFMA16(ra0, BW1[0], acc);
                acc = MFMA16(ra1, BW1[1], acc);
#pragma unroll
                for (int r = 0; r < 4; r++)
                    *(float*)(smem + OFF_R + (quad * 4 + r) * 528 + c0 * 4) = acc[r];
            }
            __syncthreads();
            // (c) strips for this jt: head h = w
            {
                const int jr = j0 + jt * 16 + l15;   // Kpb row
                bf16x8 A[4];
#pragma unroll
                for (int f = 0; f < 4; f++) {
                    const int c8 = f * 32 + quad * 8;
                    bf16x8 kp = *(const bf16x8*)(Kpb + ((size_t)w * N + jr) * HIDN + c8);
                    bf16x8 qp = *(const bf16x8*)(smem + OFF_QPB + (w * HIDN + c8) * 2);
                    const char* rbase = smem + OFF_R + l15 * 528 + c8 * 4;
                    float4 r0 = *(const float4*)(rbase);
                    float4 r1 = *(const float4*)(rbase + 16);
                    float xs[8] = {r0.x, r0.y, r0.z, r0.w, r1.x, r1.y, r1.z, r1.w};
                    union { unsigned int u[4]; bf16x8 v; } uu;
#pragma unroll
                    for (int e2 = 0; e2 < 4; e2++) {
                        float xa = silu_fast(bf2f(kp[2 * e2])     + bf2f(qp[2 * e2])     + xs[2 * e2]);
                        float xb = silu_fast(bf2f(kp[2 * e2 + 1]) + bf2f(qp[2 * e2 + 1]) + xs[2 * e2 + 1]);
                        uu.u[e2] = cvt_pk_bf16(xa, xb);
                    }
                    A[f] = uu.v;
                }
                float part[4] = {0.f, 0.f, 0.f, 0.f};
#pragma unroll 2
                for (int ct = 0; ct < 8; ct++) {
                    const int rw2 = ct * 16 + l15;
                    const char* wb = smem + OFF_W2T + rw2 * 256;
                    const int sw = (rw2 & 7) << 4;
                    bf16x8 b0 = *(const bf16x8*)(wb + ((quad * 16) ^ sw));
                    bf16x8 b1 = *(const bf16x8*)(wb + ((64 + quad * 16) ^ sw));
                    bf16x8 b2 = *(const bf16x8*)(wb + ((128 + quad * 16) ^ sw));
                    bf16x8 b3 = *(const bf16x8*)(wb + ((192 + quad * 16) ^ sw));
                    unsigned int pk = *(const unsigned int*)(smem + OFF_B2W3 + (rw2 * 9 + w) * 4);
                    float bb = bf2f((short)(pk & 0xffffu));
                    float ww = bf2f((short)(pk >> 16));
                    floatx4 acc = {bb, bb, bb, bb};
                    acc = MFMA16(A[0], b0, acc);
                    acc = MFMA16(A[1], b1, acc);
                    acc = MFMA16(A[2], b2, acc);
                    acc = MFMA16(A[3], b3, acc);
#pragma unroll
                    for (int r = 0; r < 4; r++)
                        part[r] += silu_fast(acc[r]) * ww;
                }
#pragma unroll
                for (int off = 1; off < 16; off <<= 1) {
#pragma unroll
                    for (int r = 0; r < 4; r++)
                        part[r] += __shfl_xor(part[r], off, 64);
                }
                if (l15 == 0) {
                    const int jo = j0 + jt * 16 + quad * 4;
                    float4 mv = *(const float4*)(mask + (size_t)i * N + jo);
                    float4 sv;
                    sv.x = fminf(fmaxf(part[0] + ab3v + mv.x, -1e9f), 1e9f);
                    sv.y = fminf(fmaxf(part[1] + ab3v + mv.y, -1e9f), 1e9f);
                    sv.z = fminf(fmaxf(part[2] + ab3v + mv.z, -1e9f), 1e9f);
                    sv.w = fminf(fmaxf(part[3] + ab3v + mv.w, -1e9f), 1e9f);
                    *(float4*)(scores + ((size_t)w * N + i) * N + jo) = sv;
                }
            }
            __syncthreads();
        }
    }
}

// K3: softmax + attn@V + coords out + fused (upd@wo + LN) epilogue.
__global__ __launch_bounds__(256) void k_attn2(
    const float* __restrict__ scores, const float* __restrict__ v,
    const float* __restrict__ gates, const float* __restrict__ coords,
    const float* __restrict__ ef, const float* __restrict__ wo,
    const float* __restrict__ bo, const float* __restrict__ lng,
    const float* __restrict__ lnb, float* __restrict__ out) {
    __shared__ float sA[4][N];
    __shared__ float sCrd[N * 3];
    __shared__ float sC[NHD][3];
    __shared__ float sUpd[HIDN];
    __shared__ float sR2[2];
    int i = blockIdx.x, t = threadIdx.x, w = t >> 6, lane = t & 63;
    for (int idx = t; idx < N * 3; idx += 256) sCrd[idx] = coords[idx];
    float cix = coords[i * 3], ciy = coords[i * 3 + 1], ciz = coords[i * 3 + 2];
    __syncthreads();
    for (int hh = 0; hh < 2; hh++) {
        int h = hh * 4 + w;
        const float* srow = scores + ((size_t)h * N + i) * N;
        float s[6];
#pragma unroll
        for (int p = 0; p < 6; p++) s[p] = srow[lane + 64 * p];
        float m = s[0];
#pragma unroll
        for (int p = 1; p < 6; p++) m = fmaxf(m, s[p]);
        for (int off = 1; off < 64; off <<= 1) m = fmaxf(m, __shfl_xor(m, off, 64));
        float e[6], sum = 0.f;
#pragma unroll
        for (int p = 0; p < 6; p++) { e[p] = __expf(s[p] - m); sum += e[p]; }
        for (int off = 1; off < 64; off <<= 1) sum += __shfl_xor(sum, off, 64);
        float inv = 1.0f / sum;
#pragma unroll
        for (int p = 0; p < 6; p++) sA[w][lane + 64 * p] = e[p] * inv;
        __syncthreads();
        // feats: d4 = lane&3 (float4 of dims), grp = lane>>2
        int d4 = lane & 3, grp = lane >> 2;
        float4 f4 = {0.f, 0.f, 0.f, 0.f};
        for (int j = grp; j < N; j += 16) {
            float a = sA[w][j];
            float4 vv = *(const float4*)(v + j * HIDN + h * DHD + d4 * 4);
            f4.x += a * vv.x; f4.y += a * vv.y; f4.z += a * vv.z; f4.w += a * vv.w;
        }
#pragma unroll
        for (int off = 4; off < 64; off <<= 1) {
            f4.x += __shfl_xor(f4.x, off, 64);
            f4.y += __shfl_xor(f4.y, off, 64);
            f4.z += __shfl_xor(f4.z, off, 64);
            f4.w += __shfl_xor(f4.w, off, 64);
        }
        if (lane < 4) *(float4*)(&sUpd[h * DHD + lane * 4]) = f4;
        // coords partial
        float cx = 0.f, cy = 0.f, cz = 0.f;
#pragma unroll
        for (int p = 0; p < 6; p++) {
            int j = lane + 64 * p;
            float a = sA[w][j];
            cx += a * (cix - sCrd[j * 3]);
            cy += a * (ciy - sCrd[j * 3 + 1]);
            cz += a * (ciz - sCrd[j * 3 + 2]);
        }
        for (int off = 1; off < 64; off <<= 1) {
            cx += __shfl_xor(cx, off, 64);
            cy += __shfl_xor(cy, off, 64);
            cz += __shfl_xor(cz, off, 64);
        }
        if (lane == 0) {
            float g = gates[i * NHD + h] * (1.0f / NHD);
            sC[h][0] = g * cx; sC[h][1] = g * cy; sC[h][2] = g * cz;
        }
        __syncthreads();
    }
    if (t < 3) {
        float acc = coords[i * 3 + t];
#pragma unroll
        for (int h = 0; h < NHD; h++) acc += sC[h][t];
        out[N * HIDN + i * 3 + t] = acc;
    }
    // fused k_out: y = ef + sUpd@wo + bo, LayerNorm (waves 2,3 duplicate work)
    int c = t & 127;
    float y = ef[i * HIDN + c] + bo[c];
#pragma unroll 8
    for (int cp = 0; cp < HIDN; cp++) y += sUpd[cp] * wo[cp * HIDN + c];
    float ssum = wave_sum(y);
    if (t < 128 && (t & 63) == 0) sR2[t >> 6] = ssum;
    __syncthreads();
    float mu = (sR2[0] + sR2[1]) * (1.0f / HIDN);
    __syncthreads();
    float dv = y - mu;
    float s2 = wave_sum(dv * dv);
    if (t < 128 && (t & 63) == 0) sR2[t >> 6] = s2;
    __syncthreads();
    float var = (sR2[0] + sR2[1]) * (1.0f / HIDN);
    if (t < 128) out[i * HIDN + c] = dv * rsqrtf(var + 1e-5f) * lng[c] + lnb[c];
}

extern "C" void kernel_launch(void* const* d_in, const int* in_sizes, int n_in,
                              void* d_out, int out_size, void* d_ws, size_t ws_size,
                              hipStream_t stream) {
    const float* ef      = (const float*)d_in[0];
    const float* coords  = (const float*)d_in[1];
    const float* mask    = (const float*)d_in[2];
    const float* wq      = (const float*)d_in[3];
    const float* wk      = (const float*)d_in[4];
    const float* wv      = (const float*)d_in[5];
    const float* centers = (const float*)d_in[6];
    const float* widths  = (const float*)d_in[7];
    const float* aw1     = (const float*)d_in[8];
    const float* ab1     = (const float*)d_in[9];
    const float* aw2     = (const float*)d_in[10];
    const float* ab2     = (const float*)d_in[11];
    const float* aw3     = (const float*)d_in[12];
    const float* ab3     = (const float*)d_in[13];
    const float* gw1     = (const float*)d_in[14];
    const float* gb1     = (const float*)d_in[15];
    const float* gw2     = (const float*)d_in[16];
    const float* gb2     = (const float*)d_in[17];
    const float* wo      = (const float*)d_in[18];
    const float* bo      = (const float*)d_in[19];
    const float* lng     = (const float*)d_in[20];
    const float* lnb     = (const float*)d_in[21];
    float* ws = (float*)d_ws;
    float* v      = ws + WS_V;
    unsigned short* Qpb = (unsigned short*)(ws + WS_QPB);
    unsigned short* Kpb = (unsigned short*)(ws + WS_KPB);
    float* gates  = ws + WS_GATE;
    float* scores = ws + WS_SCORES;
    unsigned short* w2bf = (unsigned short*)(ws + WS_W2BF);
    float* out = (float*)d_out;

    k_pre<<<N, 128, 0, stream>>>(ef, wq, wk, wv, aw1, aw2, gw1, gb1, gw2, gb2, v, Qpb, Kpb, gates, w2bf);
    k_scores_mfma<<<dim3(4, N), 512, 0, stream>>>(
        coords, mask, centers, widths, aw1, ab1, ab2, aw3, ab3, Qpb, Kpb, w2bf, scores);
    k_attn2<<<N, 256, 0, stream>>>(scores, v, gates, coords, ef, wo, bo, lng, lnb, out);
}